// Round 20
// baseline (30.751 us; speedup 1.0000x reference)
//
#include <hip/hip_runtime.h>

#define KS 21
#define CC 10
#define H 128
#define W 128
#define HW (H*W)
#define NCH 3
#define B 4
#define PW (W + 2*CC)          // 148 data slots per staged row

typedef _Float16 half4v __attribute__((ext_vector_type(4)));
struct __attribute__((packed)) f4u { float v[4]; };   // 4B-aligned 16B load

// LDS: dt[21][PW] packed half4 {d0,d1,d2,valid} = 24864 B; 32 B zero slot at
// 24864; sacc [16][129] float4 = 33024 B aliases everything after a barrier.
#define DT_BYTES (21*PW*8)     // 24864
#define ZSLOT    DT_BYTES      // 32 zeroed bytes (fake-tap data source)
#define SMEM_BYTES (16*129*16) // 33024

// grid (H, B), block 512 = 16 workers x 32 px-quads (r19 structure, 29.7 us).
// THIS ROUND'S SINGLE CHANGE: explicit 4-deep register prefetch pipeline.
// g0..g3 rotate through a hand-unrolled x4 loop; the ISSUE cursor runs 4 taps
// ahead of the CONSUME cursor, so 3-4 independent kern dwordx4 loads are in
// flight per wave by construction (vs ~1 when the compiler drains vmcnt each
// iteration). Uniform 28 steps; tail taps T>440 are issued with clamped
// addresses (bounded kern floats, L1-hot) and consumed against a zeroed LDS
// slot -> contribute exact +0. Accumulation order of real taps unchanged ->
// bit-identical results. Epilogue: fixed-order 16-worker in-LDS reduce +
// closed-form OOB denom + divide. No atomics, no fences, deterministic.
__global__ __launch_bounds__(512, 2)
void kaw_gather(const float* __restrict__ data,
                const float* __restrict__ kern,
                float* __restrict__ out,
                float* __restrict__ sumw)
{
    __shared__ __align__(16) unsigned char smem[SMEM_BYTES];
    unsigned char* dtB = smem;

    const int tid = threadIdx.x;
    const int t = tid & 31;         // px quad: px 4t..4t+3 (full row)
    const int w = tid >> 5;         // tap worker 0..15
    const int y = blockIdx.x;
    const int b = blockIdx.y;

    const float* __restrict__ kbase = kern + (size_t)b * (KS * KS) * HW;
    const float* __restrict__ dbase = data + (size_t)b * NCH * HW;

    // ---- stage data rows y-10..y+10, f16 {d0,d1,d2,valid}; zero the slot ----
    for (int e = tid; e < 21 * PW; e += 512) {
        int r  = e / PW;
        int c  = e - r * PW;
        int gy = y + r - CC;
        int gx = c - CC;
        half4v v = (half4v){(_Float16)0, (_Float16)0, (_Float16)0, (_Float16)0};
        if ((unsigned)gy < (unsigned)H && (unsigned)gx < (unsigned)W) {
            v.x = (_Float16)dbase[(0 * H + gy) * W + gx];
            v.y = (_Float16)dbase[(1 * H + gy) * W + gx];
            v.z = (_Float16)dbase[(2 * H + gy) * W + gx];
            v.w = (_Float16)1.0f;
        }
        *reinterpret_cast<half4v*>(dtB + e * 8) = v;
    }
    if (tid < 2) {
        *reinterpret_cast<float4*>(dtB + ZSLOT + tid * 16) =
            make_float4(0.f, 0.f, 0.f, 0.f);
    }
    __syncthreads();

    // ---- 16 accumulators: 4 px x {ch0, ch1, ch2, w} ----
    float a00 = 0.f, a01 = 0.f, a02 = 0.f, aw0 = 0.f;
    float a10 = 0.f, a11 = 0.f, a12 = 0.f, aw1 = 0.f;
    float a20 = 0.f, a21 = 0.f, a22 = 0.f, aw2 = 0.f;
    float a30 = 0.f, a31 = 0.f, a32 = 0.f, aw3 = 0.f;

    // issue cursor (4 ahead) and consume cursor; both start at T = w
    int ii = 0, jj = w, QQ = 440 - w;
    int i  = 0, j  = w, Qc = 440 - w;

#define ISSUE(gr)                                                              \
    {                                                                          \
        int Qs  = QQ < 0 ? 0 : QQ;                                             \
        int py  = y + ii - CC;                                                 \
        int pyc = py < 0 ? 0 : (py > H - 1 ? H - 1 : py);                      \
        int c0  = 4 * t + jj - CC;                                             \
        gr = *reinterpret_cast<const f4u*>(                                    \
            kbase + ((Qs << 14) + (pyc << 7) + c0));                           \
        jj += 16; QQ -= 16;                                                    \
        if (jj >= KS) { jj -= KS; ++ii; }                                      \
    }

#define STEP(gr)                                                               \
    {                                                                          \
        float e0 = __expf(gr.v[0]);                                            \
        float e1 = __expf(gr.v[1]);                                            \
        float e2 = __expf(gr.v[2]);                                            \
        float e3 = __expf(gr.v[3]);                                            \
        unsigned dpo = (Qc >= 0) ? (unsigned)(i * PW + 4 * t + j) * 8          \
                                 : (unsigned)ZSLOT;                            \
        const unsigned char* dp = dtB + dpo;                                   \
        half4v d0 = *reinterpret_cast<const half4v*>(dp +  0);                 \
        half4v d1 = *reinterpret_cast<const half4v*>(dp +  8);                 \
        half4v d2 = *reinterpret_cast<const half4v*>(dp + 16);                 \
        half4v d3 = *reinterpret_cast<const half4v*>(dp + 24);                 \
        a00 += e0 * (float)d0.x; a01 += e0 * (float)d0.y;                      \
        a02 += e0 * (float)d0.z; aw0 += e0 * (float)d0.w;                      \
        a10 += e1 * (float)d1.x; a11 += e1 * (float)d1.y;                      \
        a12 += e1 * (float)d1.z; aw1 += e1 * (float)d1.w;                      \
        a20 += e2 * (float)d2.x; a21 += e2 * (float)d2.y;                      \
        a22 += e2 * (float)d2.z; aw2 += e2 * (float)d2.w;                      \
        a30 += e3 * (float)d3.x; a31 += e3 * (float)d3.y;                      \
        a32 += e3 * (float)d3.z; aw3 += e3 * (float)d3.w;                      \
        j += 16; Qc -= 16;                                                     \
        if (j >= KS) { j -= KS; ++i; }                                         \
        ISSUE(gr)                                                              \
    }

    f4u g0, g1, g2, g3;
    ISSUE(g0) ISSUE(g1) ISSUE(g2) ISSUE(g3)          // prologue: 4 in flight
    for (int k4 = 0; k4 < 28; k4 += 4) {             // 7 rolled iterations
        STEP(g0) STEP(g1) STEP(g2) STEP(g3)
    }
#undef STEP
#undef ISSUE

    // ---- fixed-order cross-worker reduce (sacc aliases the data tile) ----
    __syncthreads();                          // all dt reads done
    float4* sacc = (float4*)smem;             // [16][129] float4, padded stride
    sacc[w * 129 + 4 * t + 0] = make_float4(a00, a01, a02, aw0);
    sacc[w * 129 + 4 * t + 1] = make_float4(a10, a11, a12, aw1);
    sacc[w * 129 + 4 * t + 2] = make_float4(a20, a21, a22, aw2);
    sacc[w * 129 + 4 * t + 3] = make_float4(a30, a31, a32, aw3);
    __syncthreads();
    if (tid < W) {
        const int px = tid;
        float r0 = 0.f, r1 = 0.f, r2 = 0.f, rw = 0.f;
        #pragma unroll
        for (int s = 0; s < 16; ++s) {        // fixed order -> deterministic
            float4 p = sacc[s * 129 + px];
            r0 += p.x; r1 += p.y; r2 += p.z; rw += p.w;
        }
        // OOB taps contribute exp(0)=1 each to the softmax denominator
        int nry = max(0, CC - y)  + max(0, y  - (H - 1 - CC));
        int nrx = max(0, CC - px) + max(0, px - (W - 1 - CC));
        float co = 21.f * nry + (float)((21 - nry) * nrx);
        float inv = 1.0f / (rw + co);
        const size_t o = (size_t)b * NCH * HW + (size_t)y * W + px;
        out[o]          = r0 * inv;
        out[o + HW]     = r1 * inv;
        out[o + 2 * HW] = r2 * inv;
        sumw[(size_t)b * HW + (size_t)y * W + px] = rw * inv;
    }
}

extern "C" void kernel_launch(void* const* d_in, const int* in_sizes, int n_in,
                              void* d_out, int out_size, void* d_ws, size_t ws_size,
                              hipStream_t stream)
{
    const float* data = (const float*)d_in[0];   // (4,3,128,128) f32
    const float* kern = (const float*)d_in[1];   // (4,441,128,128) f32
    float* out  = (float*)d_out;                 // (4,3,128,128)
    float* sumw = out + (size_t)B * NCH * HW;    // (4,1,128,128)

    dim3 g(H, B);
    kaw_gather<<<g, 512, 0, stream>>>(data, kern, out, sumw);
}

// Round 21
// 29.865 us; speedup vs baseline: 1.0297x; 1.0297x over previous
//
#include <hip/hip_runtime.h>

#define KS 21
#define CC 10
#define H 128
#define W 128
#define HW (H*W)
#define NCH 3
#define B 4
#define PW (W + 2*CC)          // 148 data slots per staged row

typedef _Float16 half4v __attribute__((ext_vector_type(4)));
struct __attribute__((packed)) f4u { float v[4]; };   // 4B-aligned 16B load

// LDS: dt[21][PW] packed half4 {d0,d1,d2,valid} = 24864 B; sacc [16][129]
// float4 = 33024 B aliases it after a barrier. Size = max of the two.
#define SMEM_BYTES (16*129*16)

// grid (H, B), block 512 = 16 workers x 32 px-quads. Block = one FULL row
// (b,y); quad t owns px 4t..4t+3, worker w = tid>>5 takes taps T = w+16k.
// Each half-wave (one worker) reads one kern plane's full row = 512 B
// contiguous per plane per wave-load. Validity-fold: data tile 4th f16
// channel = 1.0 iff in-bounds; tap loop has no compares (OOB -> exact +0;
// clamped addrs read real bounded kern floats, max overhang 536 B stays
// inside batch b's 441 planes). Epilogue: fixed-order 16-worker in-LDS
// reduce + closed-form OOB denom + divide. No atomics, no fences,
// fully deterministic. Best measured: 29.66 us (round 19).
__global__ __launch_bounds__(512, 2)
void kaw_gather(const float* __restrict__ data,
                const float* __restrict__ kern,
                float* __restrict__ out,
                float* __restrict__ sumw)
{
    __shared__ __align__(16) unsigned char smem[SMEM_BYTES];
    unsigned char* dtB = smem;

    const int tid = threadIdx.x;
    const int t = tid & 31;         // px quad: px 4t..4t+3 (full row)
    const int w = tid >> 5;         // tap worker 0..15
    const int y = blockIdx.x;
    const int b = blockIdx.y;

    const float* __restrict__ kbase = kern + (size_t)b * (KS * KS) * HW;
    const float* __restrict__ dbase = data + (size_t)b * NCH * HW;

    // ---- stage data rows y-10..y+10, cols -10..137, f16 {d0,d1,d2,valid} ----
    for (int e = tid; e < 21 * PW; e += 512) {
        int r  = e / PW;                     // compiler magic-div (exact)
        int c  = e - r * PW;
        int gy = y + r - CC;
        int gx = c - CC;
        half4v v = (half4v){(_Float16)0, (_Float16)0, (_Float16)0, (_Float16)0};
        if ((unsigned)gy < (unsigned)H && (unsigned)gx < (unsigned)W) {
            v.x = (_Float16)dbase[(0 * H + gy) * W + gx];
            v.y = (_Float16)dbase[(1 * H + gy) * W + gx];
            v.z = (_Float16)dbase[(2 * H + gy) * W + gx];
            v.w = (_Float16)1.0f;
        }
        *reinterpret_cast<half4v*>(dtB + e * 8) = v;
    }
    __syncthreads();

    // ---- 16 accumulators: 4 px x {ch0, ch1, ch2, w} ----
    float a00 = 0.f, a01 = 0.f, a02 = 0.f, aw0 = 0.f;
    float a10 = 0.f, a11 = 0.f, a12 = 0.f, aw1 = 0.f;
    float a20 = 0.f, a21 = 0.f, a22 = 0.f, aw2 = 0.f;
    float a30 = 0.f, a31 = 0.f, a32 = 0.f, aw3 = 0.f;

    // 441 = 9*28 + 7*27: workers 0..8 take 28 taps, 9..15 take 27.
    const int ntap = (w < 9) ? 28 : 27;
    int i = 0, j = w, Q = 440 - w;          // w < 16 < 21
    #pragma unroll 4
    for (int k = 0; k < ntap; ++k) {
        int py  = y + i - CC;
        int pyc = py < 0 ? 0 : (py > H - 1 ? H - 1 : py);   // addr-safe row
        int c0  = 4 * t + j - CC;            // kern/data col of elem 0
        // c0 < 0 only for j < 10, where Q >= 1 -> address stays in-bounds;
        // c0 > 124 overhangs into adjacent real kern floats (x0 = exact +0).
        f4u g = *reinterpret_cast<const f4u*>(
            kbase + ((Q << 14) + (pyc << 7) + c0));
        float e0 = __expf(g.v[0]);
        float e1 = __expf(g.v[1]);
        float e2 = __expf(g.v[2]);
        float e3 = __expf(g.v[3]);
        const unsigned char* dp = dtB + (unsigned)(i * PW + 4 * t + j) * 8;
        half4v d0 = *reinterpret_cast<const half4v*>(dp +  0);
        half4v d1 = *reinterpret_cast<const half4v*>(dp +  8);
        half4v d2 = *reinterpret_cast<const half4v*>(dp + 16);
        half4v d3 = *reinterpret_cast<const half4v*>(dp + 24);
        a00 += e0 * (float)d0.x; a01 += e0 * (float)d0.y; a02 += e0 * (float)d0.z; aw0 += e0 * (float)d0.w;
        a10 += e1 * (float)d1.x; a11 += e1 * (float)d1.y; a12 += e1 * (float)d1.z; aw1 += e1 * (float)d1.w;
        a20 += e2 * (float)d2.x; a21 += e2 * (float)d2.y; a22 += e2 * (float)d2.z; aw2 += e2 * (float)d2.w;
        a30 += e3 * (float)d3.x; a31 += e3 * (float)d3.y; a32 += e3 * (float)d3.z; aw3 += e3 * (float)d3.w;
        // advance T += 16: j += 16 (mod 21, wraps at most once), Q -= 16
        j += 16; Q -= 16;
        if (j >= KS) { j -= KS; ++i; }
    }

    // ---- fixed-order cross-worker reduce (sacc aliases the data tile) ----
    __syncthreads();                          // all dt reads done
    float4* sacc = (float4*)smem;             // [16][129] float4, padded stride
    sacc[w * 129 + 4 * t + 0] = make_float4(a00, a01, a02, aw0);
    sacc[w * 129 + 4 * t + 1] = make_float4(a10, a11, a12, aw1);
    sacc[w * 129 + 4 * t + 2] = make_float4(a20, a21, a22, aw2);
    sacc[w * 129 + 4 * t + 3] = make_float4(a30, a31, a32, aw3);
    __syncthreads();
    if (tid < W) {
        const int px = tid;
        float r0 = 0.f, r1 = 0.f, r2 = 0.f, rw = 0.f;
        #pragma unroll
        for (int s = 0; s < 16; ++s) {        // fixed order -> deterministic
            float4 p = sacc[s * 129 + px];
            r0 += p.x; r1 += p.y; r2 += p.z; rw += p.w;
        }
        // OOB taps contribute exp(0)=1 each to the softmax denominator
        int nry = max(0, CC - y)  + max(0, y  - (H - 1 - CC));
        int nrx = max(0, CC - px) + max(0, px - (W - 1 - CC));
        float co = 21.f * nry + (float)((21 - nry) * nrx);
        float inv = 1.0f / (rw + co);
        const size_t o = (size_t)b * NCH * HW + (size_t)y * W + px;
        out[o]          = r0 * inv;
        out[o + HW]     = r1 * inv;
        out[o + 2 * HW] = r2 * inv;
        sumw[(size_t)b * HW + (size_t)y * W + px] = rw * inv;
    }
}

extern "C" void kernel_launch(void* const* d_in, const int* in_sizes, int n_in,
                              void* d_out, int out_size, void* d_ws, size_t ws_size,
                              hipStream_t stream)
{
    const float* data = (const float*)d_in[0];   // (4,3,128,128) f32
    const float* kern = (const float*)d_in[1];   // (4,441,128,128) f32
    float* out  = (float*)d_out;                 // (4,3,128,128)
    float* sumw = out + (size_t)B * NCH * HW;    // (4,1,128,128)

    dim3 g(H, B);
    kaw_gather<<<g, 512, 0, stream>>>(data, kern, out, sumw);
}